// Round 1
// baseline (204.269 us; speedup 1.0000x reference)
//
#include <hip/hip_runtime.h>
#include <math.h>

#define NQ 131072
#define MN 8192
#define DEPTHT 16
#define EPSD 1e-6f
#define BIGD 1e9f

// ---------------------------------------------------------------------------
// Kernel 1: MLP 2 -> 100 -> 100 -> 30 -> 2 over concatenated rows
// rows [0, NQ)        : queries  (from x)
// rows [NQ, NQ+MN)    : nodes    (from node_data)
// Output: ws as [NQ+MN][2] floats (qx rows first, then emb rows).
// Weight accesses are wave-uniform (loop-counter indices) -> scalar s_load
// broadcasts; h2[100]/h3[30] live in VGPRs via constant-index unrolled loops.
// ---------------------------------------------------------------------------
__global__ __launch_bounds__(256) void mlp_kernel(
    const float* __restrict__ x, const float* __restrict__ nd,
    const float* __restrict__ W1, const float* __restrict__ b1,
    const float* __restrict__ W2, const float* __restrict__ b2,
    const float* __restrict__ W3, const float* __restrict__ b3,
    const float* __restrict__ W4, const float* __restrict__ b4,
    float* __restrict__ outv)
{
    const int r = blockIdx.x * 256 + threadIdx.x;   // grid sized exactly
    const float2* src = (r < NQ) ? ((const float2*)x + r)
                                 : ((const float2*)nd + (r - NQ));
    const float2 xi = *src;
    const float x0 = xi.x, x1 = xi.y;

    // layer 1 fused into layer 2: h1[k] recomputed from (x0,x1) per k (2 FMA)
    float h2[100];
#pragma unroll
    for (int j = 0; j < 100; ++j) h2[j] = b2[j];

    for (int k = 0; k < 100; ++k) {
        float h1k = fmaf(x0, W1[k], fmaf(x1, W1[100 + k], b1[k]));
        h1k = fmaxf(h1k, 0.0f);
        const float* w2row = W2 + k * 100;
#pragma unroll
        for (int j = 0; j < 100; ++j) h2[j] = fmaf(h1k, w2row[j], h2[j]);
    }
#pragma unroll
    for (int j = 0; j < 100; ++j) h2[j] = fmaxf(h2[j], 0.0f);

    // layer 3: 100 -> 30 (k fully unrolled so h2[k] stays register-resident)
    float h3[30];
#pragma unroll
    for (int j = 0; j < 30; ++j) h3[j] = b3[j];
#pragma unroll
    for (int k = 0; k < 100; ++k) {
        const float* w3row = W3 + k * 30;
#pragma unroll
        for (int j = 0; j < 30; ++j) h3[j] = fmaf(h2[k], w3row[j], h3[j]);
    }

    // layer 4: 30 -> 2
    float o0 = b4[0], o1 = b4[1];
#pragma unroll
    for (int k = 0; k < 30; ++k) {
        const float h = fmaxf(h3[k], 0.0f);
        o0 = fmaf(h, W4[2 * k],     o0);
        o1 = fmaf(h, W4[2 * k + 1], o1);
    }

    float2* dst = (float2*)outv + r;
    *dst = make_float2(o0, o1);
}

// ---------------------------------------------------------------------------
// Kernel 2: per-query tree traversal.
// emb (64 KB) staged in LDS per block (2 blocks/CU). children + classes from
// global (fully L2-resident: 256 KB + 64 KB). One thread per query.
// ---------------------------------------------------------------------------
__global__ __launch_bounds__(256) void traverse_kernel(
    const float* __restrict__ qx, const float2* __restrict__ emb,
    const float2* __restrict__ cls, const int* __restrict__ children,
    float* __restrict__ out)
{
    __shared__ float2 semb[MN];
    {
        const float4* gsrc = (const float4*)emb;
        float4* sdst = (float4*)semb;
#pragma unroll
        for (int t = 0; t < (MN * 2 / 4) / 256; ++t)
            sdst[threadIdx.x + t * 256] = gsrc[threadIdx.x + t * 256];
    }
    __syncthreads();

    const int q = blockIdx.x * 256 + threadIdx.x;   // grid sized exactly
    const float2 qv = ((const float2*)qx)[q];
    const float q0 = qv.x, q1 = qv.y;

    int cur = 0;
    float2 ecur = semb[0];
    float prob = 0.0f;
    float out0 = 0.0f, out1 = 0.0f;
    bool done = false;

    for (int t = 0; t < DEPTHT; ++t) {
        if (__all(done)) break;
        if (!done) {
            const int4* crow = (const int4*)(children + cur * 8);
            const int4 ca = crow[0], cb = crow[1];
            int ci[8] = {ca.x, ca.y, ca.z, ca.w, cb.x, cb.y, cb.z, cb.w};

            // distance current node -> query
            float dx0 = ecur.x - q0 + EPSD;
            float dy0 = ecur.y - q1 + EPSD;
            const float d0 = sqrtf(dx0 * dx0 + dy0 * dy0);

            float dc[8];
            float2 ce[8];
#pragma unroll
            for (int j = 0; j < 8; ++j) {
                const bool v = ci[j] >= 0;
                const int idx = v ? ci[j] : 0;
                const float2 e = semb[idx];
                ce[j] = e;
                const float dx = e.x - q0 + EPSD;
                const float dy = e.y - q1 + EPSD;
                dc[j] = v ? sqrtf(dx * dx + dy * dy) : BIGD;
            }

            // argmax(log_softmax(-all_d)) == first argmin(all_d)
            float dmin = d0;
            int amax = 0;
#pragma unroll
            for (int j = 0; j < 8; ++j)
                if (dc[j] < dmin) { dmin = dc[j]; amax = j + 1; }

            // max logp = -log(sum exp(dmin - d_i)); BIG pads underflow to 0
            float s = expf(dmin - d0);
#pragma unroll
            for (int j = 0; j < 8; ++j) s += expf(dmin - dc[j]);
            const float max_prob = -logf(s);

            // quirk: t==0 adds max_prob twice
            const float prob_new = prob + max_prob + ((t == 0) ? max_prob : 0.0f);

            if (amax == 0) {
                bool has_child = false;
#pragma unroll
                for (int j = 0; j < 8; ++j) has_child |= (ci[j] >= 0);
                if (has_child) {
                    // softmax(-d2) weighted class mixture
                    float d2[8];
                    float m2 = BIGD;
#pragma unroll
                    for (int j = 0; j < 8; ++j) {
                        const float dx = ecur.x - ce[j].x + EPSD;
                        const float dy = ecur.y - ce[j].y + EPSD;
                        d2[j] = (ci[j] >= 0) ? sqrtf(dx * dx + dy * dy) : BIGD;
                        m2 = fminf(m2, d2[j]);
                    }
                    float s2 = 0.0f, mix0 = 0.0f, mix1 = 0.0f;
#pragma unroll
                    for (int j = 0; j < 8; ++j) {
                        const float w = expf(m2 - d2[j]);  // exactly 0 for pads
                        s2 += w;
                        if (ci[j] >= 0) {
                            const float2 c = cls[ci[j]];
                            mix0 = fmaf(w, c.x, mix0);
                            mix1 = fmaf(w, c.y, mix1);
                        }
                    }
                    mix0 /= s2;
                    mix1 /= s2;
                    out0 = prob_new + logf(fmaxf(mix0, 1e-30f));
                    out1 = prob_new + logf(fmaxf(mix1, 1e-30f));
                } else {
                    out0 = prob_new;
                    out1 = prob_new;
                }
                done = true;
            } else {
                cur  = ci[amax - 1];
                ecur = ce[amax - 1];
                prob = prob_new;
            }
        }
    }

    ((float2*)out)[q] = make_float2(out0, out1);
}

// ---------------------------------------------------------------------------
extern "C" void kernel_launch(void* const* d_in, const int* in_sizes, int n_in,
                              void* d_out, int out_size, void* d_ws, size_t ws_size,
                              hipStream_t stream)
{
    const float* x        = (const float*)d_in[0];
    const float* nd       = (const float*)d_in[1];
    const float* cls      = (const float*)d_in[2];
    const int*   children = (const int*)d_in[3];
    const float* W1 = (const float*)d_in[4];
    const float* b1 = (const float*)d_in[5];
    const float* W2 = (const float*)d_in[6];
    const float* b2 = (const float*)d_in[7];
    const float* W3 = (const float*)d_in[8];
    const float* b3 = (const float*)d_in[9];
    const float* W4 = (const float*)d_in[10];
    const float* b4 = (const float*)d_in[11];

    float* ws = (float*)d_ws;   // [NQ+MN][2] floats: qx rows then emb rows

    mlp_kernel<<<(NQ + MN) / 256, 256, 0, stream>>>(
        x, nd, W1, b1, W2, b2, W3, b3, W4, b4, ws);

    traverse_kernel<<<NQ / 256, 256, 0, stream>>>(
        ws, (const float2*)(ws + 2 * NQ), (const float2*)cls, children,
        (float*)d_out);
}